// Round 2
// baseline (989.244 us; speedup 1.0000x reference)
//
#include <hip/hip_runtime.h>
#include <hip/hip_bf16.h>

#define EBLK 128

// ---------- helpers ----------
static __device__ __forceinline__ float bf2f(unsigned int b) { return __uint_as_float(b << 16); }
static __device__ __forceinline__ float silu(float x) { return x / (1.0f + __expf(-x)); }

// load `count` logical f32 values from an array that is either bf16 or f32
static __device__ __forceinline__ float load1(const void* p, long off, int isbf) {
    return isbf ? bf2f(((const unsigned short*)p)[off]) : ((const float*)p)[off];
}
static __device__ __forceinline__ void load8(const void* p, long off, int isbf, float* o) {
    if (isbf) {
        uint4 v = *(const uint4*)((const unsigned short*)p + off);
        o[0]=bf2f(v.x&0xffffu); o[1]=bf2f(v.x>>16);
        o[2]=bf2f(v.y&0xffffu); o[3]=bf2f(v.y>>16);
        o[4]=bf2f(v.z&0xffffu); o[5]=bf2f(v.z>>16);
        o[6]=bf2f(v.w&0xffffu); o[7]=bf2f(v.w>>16);
    } else {
        const float4* q = (const float4*)((const float*)p + off);
        float4 a = q[0], b = q[1];
        o[0]=a.x; o[1]=a.y; o[2]=a.z; o[3]=a.w;
        o[4]=b.x; o[5]=b.y; o[6]=b.z; o[7]=b.w;
    }
}
static __device__ __forceinline__ void load4(const void* p, long off, int isbf, float* o) {
    if (isbf) {
        uint2 v = *(const uint2*)((const unsigned short*)p + off);
        o[0]=bf2f(v.x&0xffffu); o[1]=bf2f(v.x>>16);
        o[2]=bf2f(v.y&0xffffu); o[3]=bf2f(v.y>>16);
    } else {
        float4 v = *(const float4*)((const float*)p + off);
        o[0]=v.x; o[1]=v.y; o[2]=v.z; o[3]=v.w;
    }
}

// ---------- dtype detector ----------
// bf16-pair words: low 16 bits are a bf16 of N(0,1) data -> exponent field in
// [118,132] with prob ~0.999. f32 words: low 16 bits are uniform mantissa bits
// -> ~6% in-window. 256 samples, threshold 128.
__global__ void k_detect(const unsigned int* __restrict__ w, int* __restrict__ flag) {
    if (blockIdx.x == 0 && threadIdx.x == 0) {
        int hits = 0;
        for (int i = 0; i < 256; i++) {
            unsigned int e = (w[i] >> 7) & 0xFFu;  // exponent field of low half-word as bf16
            if (e >= 118u && e <= 132u) hits++;
        }
        *flag = (hits >= 128) ? 1 : 0;
    }
}

// ---------- weights bf16/f32 -> pre-scaled f32 ----------
// Wf layout: [w1: 512 | w2: 4096 | w3: 4096 | w4: 1024]
__global__ void k_weights(const void* __restrict__ w1, const void* __restrict__ w2,
                          const void* __restrict__ w3, const void* __restrict__ w4,
                          const int* __restrict__ flag, float* __restrict__ Wf) {
    int idx = blockIdx.x * 256 + threadIdx.x;
    if (idx >= 9728) return;
    const int isbf = *flag;
    float v, s;
    if (idx < 512)       { v = load1(w1, idx, isbf);        s = 0.35355339059327373f; }
    else if (idx < 4608) { v = load1(w2, idx - 512, isbf);  s = 0.125f; }
    else if (idx < 8704) { v = load1(w3, idx - 4608, isbf); s = 0.125f; }
    else                 { v = load1(w4, idx - 8704, isbf); s = 0.125f; }
    Wf[idx] = v * s;
}

// ---------- per-node projections, constants folded ----------
// NA[n*32 + u]           = c        * sum_v node0[n,v]    * W0[u,v]
// NA[n*32 + 8 + u*3 + k] = c/sqrt3  * sum_v node1[n,v,k]  * W1[u,v]
__global__ void k_nodeA(const void* __restrict__ nf, const void* __restrict__ W0,
                        const void* __restrict__ W1, const int* __restrict__ flag,
                        float* __restrict__ NA, int n_nodes) {
    int t = blockIdx.x * 256 + threadIdx.x;
    int n = t >> 5;
    int c = t & 31;
    if (n >= n_nodes) return;
    const int isbf = *flag;
    float sum = 0.0f;
    if (c < 8) {
        #pragma unroll 8
        for (int v = 0; v < 64; v++)
            sum += load1(nf, (long)n * 256 + v, isbf) * load1(W0, c * 64 + v, isbf);
        NA[(long)n * 32 + c] = sum * 0.03125f;                   // 1/sqrt(8*64*2)
    } else {
        int u  = (c - 8) / 3;
        int kk = (c - 8) % 3;
        #pragma unroll 8
        for (int v = 0; v < 64; v++)
            sum += load1(nf, (long)n * 256 + 64 + v * 3 + kk, isbf) * load1(W1, u * 64 + v, isbf);
        NA[(long)n * 32 + c] = sum * 0.018042195912175804f;      // (1/32)/sqrt(3)
    }
}

// ---------- primary per-edge kernel: MLP + contraction + scalar atomic ----------
__global__ __launch_bounds__(EBLK) void k_edges(
    const void* __restrict__ ef, const void* __restrict__ ea, const void* __restrict__ qc,
    const int* __restrict__ eidx, const int* __restrict__ flag,
    const float* __restrict__ Wf, const float* __restrict__ NA,
    float* __restrict__ acc, int n_edges) {
    __shared__ float hs[EBLK * 65];
    const int tid = threadIdx.x;
    const int e = blockIdx.x * EBLK + tid;
    if (e >= n_edges) return;
    const int isbf = *flag;
    float* hrow = &hs[tid * 65];

    const float* W1f = Wf;
    const float* W2f = Wf + 512;
    const float* W3f = Wf + 4608;
    const float* W4f = Wf + 8704;

    float efr[8];
    load8(ef, (long)e * 8, isbf, efr);

    float a[64];
    #pragma unroll
    for (int j = 0; j < 64; j++) a[j] = 0.0f;
    #pragma unroll
    for (int i = 0; i < 8; i++) {
        const float hi = efr[i];
        const float* wr = W1f + i * 64;
        #pragma unroll
        for (int j = 0; j < 64; j++) a[j] += hi * wr[j];
    }
    #pragma unroll
    for (int j = 0; j < 64; j++) hrow[j] = silu(a[j]);

    #pragma unroll
    for (int j = 0; j < 64; j++) a[j] = 0.0f;
    #pragma unroll 4
    for (int i = 0; i < 64; i++) {
        const float hi = hrow[i];
        const float* wr = W2f + i * 64;
        #pragma unroll
        for (int j = 0; j < 64; j++) a[j] += hi * wr[j];
    }
    #pragma unroll
    for (int j = 0; j < 64; j++) hrow[j] = silu(a[j]);

    #pragma unroll
    for (int j = 0; j < 64; j++) a[j] = 0.0f;
    #pragma unroll 4
    for (int i = 0; i < 64; i++) {
        const float hi = hrow[i];
        const float* wr = W3f + i * 64;
        #pragma unroll
        for (int j = 0; j < 64; j++) a[j] += hi * wr[j];
    }
    #pragma unroll
    for (int j = 0; j < 64; j++) hrow[j] = silu(a[j]);

    float tp[16];
    #pragma unroll
    for (int c = 0; c < 16; c++) tp[c] = 0.0f;
    #pragma unroll 4
    for (int i = 0; i < 64; i++) {
        const float hi = hrow[i];
        const float* wr = W4f + i * 16;
        #pragma unroll
        for (int c = 0; c < 16; c++) tp[c] += hi * wr[c];
    }

    const int s = eidx[e];
    const int r = eidx[n_edges + e];

    float qr[8];
    load8(qc, (long)s * 8, isbf, qr);
    float eav[4];
    load4(ea, (long)e * 4, isbf, eav);

    float nav[32];
    {
        const float4* np4 = (const float4*)(NA + (long)r * 32);
        #pragma unroll
        for (int i = 0; i < 8; i++) {
            float4 v = np4[i];
            nav[i*4+0] = v.x; nav[i*4+1] = v.y; nav[i*4+2] = v.z; nav[i*4+3] = v.w;
        }
    }

    float contrib = 0.0f;
    #pragma unroll
    for (int u = 0; u < 8; u++) {
        const float wq0 = tp[u] * qr[u];
        const float wq1 = tp[8 + u] * qr[u];
        contrib += wq0 * eav[0] * nav[u];
        contrib += wq1 * (eav[1] * nav[8 + u*3 + 0] +
                          eav[2] * nav[8 + u*3 + 1] +
                          eav[3] * nav[8 + u*3 + 2]);
    }
    atomicAdd(&acc[r], contrib);
}

// ---------- fallback per-edge kernel (tiny workspace): fuses node projection ----------
__global__ __launch_bounds__(EBLK) void k_edges_fused(
    const void* __restrict__ ef, const void* __restrict__ ea, const void* __restrict__ qc,
    const void* __restrict__ nf, const void* __restrict__ W0, const void* __restrict__ W1,
    const void* __restrict__ w1, const void* __restrict__ w2,
    const void* __restrict__ w3, const void* __restrict__ w4,
    const int* __restrict__ eidx, const int* __restrict__ flag,
    float* __restrict__ acc, int n_edges) {
    __shared__ float hs[EBLK * 65];
    const int tid = threadIdx.x;
    const int e = blockIdx.x * EBLK + tid;
    if (e >= n_edges) return;
    const int isbf = *flag;
    float* hrow = &hs[tid * 65];

    float efr[8];
    load8(ef, (long)e * 8, isbf, efr);

    float a[64];
    #pragma unroll
    for (int j = 0; j < 64; j++) a[j] = 0.0f;
    #pragma unroll
    for (int i = 0; i < 8; i++) {
        const float hi = efr[i];
        #pragma unroll 16
        for (int j = 0; j < 64; j++) a[j] += hi * load1(w1, i * 64 + j, isbf);
    }
    #pragma unroll
    for (int j = 0; j < 64; j++) hrow[j] = silu(a[j] * 0.35355339059327373f);

    #pragma unroll
    for (int j = 0; j < 64; j++) a[j] = 0.0f;
    #pragma unroll 2
    for (int i = 0; i < 64; i++) {
        const float hi = hrow[i];
        #pragma unroll 16
        for (int j = 0; j < 64; j++) a[j] += hi * load1(w2, i * 64 + j, isbf);
    }
    #pragma unroll
    for (int j = 0; j < 64; j++) hrow[j] = silu(a[j] * 0.125f);

    #pragma unroll
    for (int j = 0; j < 64; j++) a[j] = 0.0f;
    #pragma unroll 2
    for (int i = 0; i < 64; i++) {
        const float hi = hrow[i];
        #pragma unroll 16
        for (int j = 0; j < 64; j++) a[j] += hi * load1(w3, i * 64 + j, isbf);
    }
    #pragma unroll
    for (int j = 0; j < 64; j++) hrow[j] = silu(a[j] * 0.125f);

    float tp[16];
    #pragma unroll
    for (int c = 0; c < 16; c++) tp[c] = 0.0f;
    #pragma unroll 2
    for (int i = 0; i < 64; i++) {
        const float hi = hrow[i];
        #pragma unroll
        for (int c = 0; c < 16; c++) tp[c] += hi * load1(w4, i * 16 + c, isbf);
    }
    #pragma unroll
    for (int c = 0; c < 16; c++) tp[c] *= 0.125f;

    const int s = eidx[e];
    const int r = eidx[n_edges + e];

    float qr[8];
    load8(qc, (long)s * 8, isbf, qr);
    float eav[4];
    load4(ea, (long)e * 4, isbf, eav);

    // on-the-fly node projections
    float a0[8], a1k[8][3];
    #pragma unroll
    for (int u = 0; u < 8; u++) { a0[u] = 0.0f; a1k[u][0]=0.0f; a1k[u][1]=0.0f; a1k[u][2]=0.0f; }
    for (int v = 0; v < 64; v++) {
        const float n0 = load1(nf, (long)r * 256 + v, isbf);
        const float n1x = load1(nf, (long)r * 256 + 64 + v * 3 + 0, isbf);
        const float n1y = load1(nf, (long)r * 256 + 64 + v * 3 + 1, isbf);
        const float n1z = load1(nf, (long)r * 256 + 64 + v * 3 + 2, isbf);
        #pragma unroll
        for (int u = 0; u < 8; u++) {
            const float w0v = load1(W0, u * 64 + v, isbf);
            const float w1v = load1(W1, u * 64 + v, isbf);
            a0[u] += n0 * w0v;
            a1k[u][0] += n1x * w1v;
            a1k[u][1] += n1y * w1v;
            a1k[u][2] += n1z * w1v;
        }
    }

    float contrib = 0.0f;
    #pragma unroll
    for (int u = 0; u < 8; u++) {
        const float wq0 = tp[u] * qr[u];
        const float wq1 = tp[8 + u] * qr[u];
        contrib += wq0 * eav[0] * a0[u] * 0.03125f;
        contrib += wq1 * (eav[1] * a1k[u][0] + eav[2] * a1k[u][1] + eav[3] * a1k[u][2])
                       * 0.018042195912175804f;
    }
    atomicAdd(&acc[r], contrib);
}

// ---------- accumulator -> output (bf16 or f32 per flag) ----------
__global__ void k_out(const float* __restrict__ acc, void* __restrict__ out,
                      const int* __restrict__ flag, int n) {
    int i = blockIdx.x * 256 + threadIdx.x;
    if (i >= n) return;
    if (*flag) ((__hip_bfloat16*)out)[i] = __float2bfloat16(acc[i]);
    else       ((float*)out)[i] = acc[i];
}

// ---------- launch ----------
extern "C" void kernel_launch(void* const* d_in, const int* in_sizes, int n_in,
                              void* d_out, int out_size, void* d_ws, size_t ws_size,
                              hipStream_t stream) {
    const void* node_feats      = d_in[0];
    const void* charges_induced = d_in[2];
    const void* edge_feats      = d_in[3];
    const void* edge_attrs      = d_in[4];
    const void* mlp_w1          = d_in[6];
    const void* mlp_w2          = d_in[7];
    const void* mlp_w3          = d_in[8];
    const void* mlp_w4          = d_in[9];
    const void* W0              = d_in[10];
    const void* W1              = d_in[11];
    const int*  edge_index      = (const int*)d_in[12];

    const int n_nodes = in_sizes[0] / 256;   // NODE_MULT*4
    const int n_edges = in_sizes[3] / 8;     // RBF

    int*   flag = (int*)d_ws;
    float* base = (float*)((char*)d_ws + 256);

    const size_t need_big = 256 + (size_t)9728 * 4
                          + (size_t)n_nodes * 32 * 4 + (size_t)n_nodes * 4;

    k_detect<<<1, 64, 0, stream>>>((const unsigned int*)node_feats, flag);

    if (ws_size >= need_big) {
        float* Wf  = base;                          // 9728 f32
        float* NA  = Wf + 9728;                     // n_nodes*32 f32
        float* acc = NA + (size_t)n_nodes * 32;     // n_nodes f32

        hipMemsetAsync(acc, 0, (size_t)n_nodes * sizeof(float), stream);
        k_weights<<<38, 256, 0, stream>>>(mlp_w1, mlp_w2, mlp_w3, mlp_w4, flag, Wf);
        k_nodeA<<<(n_nodes * 32 + 255) / 256, 256, 0, stream>>>(node_feats, W0, W1, flag, NA, n_nodes);
        k_edges<<<(n_edges + EBLK - 1) / EBLK, EBLK, 0, stream>>>(
            edge_feats, edge_attrs, charges_induced, edge_index, flag, Wf, NA, acc, n_edges);
        k_out<<<(n_nodes + 255) / 256, 256, 0, stream>>>(acc, d_out, flag, n_nodes);
    } else {
        float* acc = base;                          // n_nodes f32
        hipMemsetAsync(acc, 0, (size_t)n_nodes * sizeof(float), stream);
        k_edges_fused<<<(n_edges + EBLK - 1) / EBLK, EBLK, 0, stream>>>(
            edge_feats, edge_attrs, charges_induced, node_feats, W0, W1,
            mlp_w1, mlp_w2, mlp_w3, mlp_w4, edge_index, flag, acc, n_edges);
        k_out<<<(n_nodes + 255) / 256, 256, 0, stream>>>(acc, d_out, flag, n_nodes);
    }
}

// Round 3
// 502.263 us; speedup vs baseline: 1.9696x; 1.9696x over previous
//
#include <hip/hip_runtime.h>
#include <hip/hip_bf16.h>

typedef short short8 __attribute__((ext_vector_type(8)));
typedef float f32x4 __attribute__((ext_vector_type(4)));

// ---------- helpers ----------
static __device__ __forceinline__ float bf2f(unsigned int b) { return __uint_as_float(b << 16); }
static __device__ __forceinline__ short fb2s(float x) {       // f32 -> bf16 bits (RNE)
    unsigned u = __float_as_uint(x);
    return (short)((u + 0x7FFFu + ((u >> 16) & 1u)) >> 16);
}
static __device__ __forceinline__ float silu(float x) { return x / (1.0f + __expf(-x)); }
static __device__ __forceinline__ float load1(const void* p, long off, int isbf) {
    return isbf ? bf2f(((const unsigned short*)p)[off]) : ((const float*)p)[off];
}
static __device__ __forceinline__ void load4(const void* p, long off, int isbf, float* o) {
    if (isbf) {
        uint2 v = *(const uint2*)((const unsigned short*)p + off);
        o[0]=bf2f(v.x&0xffffu); o[1]=bf2f(v.x>>16);
        o[2]=bf2f(v.y&0xffffu); o[3]=bf2f(v.y>>16);
    } else {
        float4 v = *(const float4*)((const float*)p + off);
        o[0]=v.x; o[1]=v.y; o[2]=v.z; o[3]=v.w;
    }
}

// ---------- dtype detector (bf16 vs f32), parallel ----------
__global__ void k_detect(const unsigned int* __restrict__ w, int* __restrict__ flag) {
    int lane = threadIdx.x & 63;
    unsigned int e = (w[lane] >> 7) & 0xFFu;    // exponent of low half-word viewed as bf16
    unsigned long long m = __ballot(e >= 118u && e <= 132u);
    if (lane == 0) *flag = (__popcll(m) >= 32) ? 1 : 0;
}

// ---------- prepack MLP weights into MFMA B-fragment layout (bf16) ----------
// 22 tiles x 512 shorts. tile: [0,4)=L1(t,kt=0,K pad 8->32), [4,12)=L2(t*2+kt),
// [12,20)=L3, [20,22)=L4(kt). frag elem: B[k = kt*32+(lane>>4)*8+j][n = t*16+(lane&15)]
__global__ void k_prepack(const void* __restrict__ w1, const void* __restrict__ w2,
                          const void* __restrict__ w3, const void* __restrict__ w4,
                          const int* __restrict__ flag, short* __restrict__ Bws) {
    int idx = blockIdx.x * 256 + threadIdx.x;
    if (idx >= 11264) return;
    const int isbf = *flag;
    int j = idx & 7, lane = (idx >> 3) & 63, tile = idx >> 9;
    int n16 = lane & 15, kq = lane >> 4;
    float v;
    if (tile < 4) {                       // layer1: K=8 (padded), no scale here
        int k = kq * 8 + j, n = tile * 16 + n16;
        v = (k < 8) ? load1(w1, k * 64 + n, isbf) : 0.0f;
    } else if (tile < 12) {               // layer2, scale 1/8 (exact in bf16)
        int t = (tile - 4) >> 1, kt = (tile - 4) & 1;
        int k = kt * 32 + kq * 8 + j, n = t * 16 + n16;
        v = load1(w2, k * 64 + n, isbf) * 0.125f;
    } else if (tile < 20) {               // layer3
        int t = (tile - 12) >> 1, kt = (tile - 12) & 1;
        int k = kt * 32 + kq * 8 + j, n = t * 16 + n16;
        v = load1(w3, k * 64 + n, isbf) * 0.125f;
    } else {                              // layer4: 64x16
        int kt = tile - 20;
        int k = kt * 32 + kq * 8 + j, n = n16;
        v = load1(w4, k * 16 + n, isbf) * 0.125f;
    }
    Bws[idx] = fb2s(v);
}

// ---------- per-node projections: wave per node, 2 lanes per output ----------
__global__ __launch_bounds__(256) void k_nodeA(
    const void* __restrict__ nf, const void* __restrict__ W0, const void* __restrict__ W1,
    const int* __restrict__ flag, float* __restrict__ NA, int n_nodes) {
    const int isbf = *flag;
    int tid = threadIdx.x, wv = tid >> 6, lane = tid & 63;
    int nraw = blockIdx.x * 4 + wv;
    bool valid = nraw < n_nodes;
    long n = valid ? nraw : (n_nodes - 1);
    int c = lane & 31, h = lane >> 5;
    float sum = 0.0f, scale;
    if (c < 8) {
        #pragma unroll 8
        for (int v = h * 32; v < h * 32 + 32; v++)
            sum += load1(nf, n * 256 + v, isbf) * load1(W0, c * 64 + v, isbf);
        scale = 0.03125f;                         // 1/sqrt(8*64*2)
    } else {
        int u = (c - 8) / 3, kk = (c - 8) % 3;
        #pragma unroll 8
        for (int v = h * 32; v < h * 32 + 32; v++)
            sum += load1(nf, n * 256 + 64 + v * 3 + kk, isbf) * load1(W1, u * 64 + v, isbf);
        scale = 0.018042195912175804f;            // (1/32)/sqrt(3)
    }
    sum += __shfl_xor(sum, 32);
    if (h == 0 && valid) NA[n * 32 + c] = sum * scale;
}

// ---------- MFMA edge kernel: 256 thr = 4 waves, 32 edges/wave ----------
__global__ __launch_bounds__(256) void k_edges_mfma(
    const void* __restrict__ ef, const void* __restrict__ ea, const void* __restrict__ qc,
    const int* __restrict__ eidx, const int* __restrict__ flag,
    const short* __restrict__ Bws, const float* __restrict__ NA,
    float* __restrict__ acc, int n_edges) {
    __shared__ short W[11264];                 // weights, B-fragment layout
    __shared__ short Hs[4 * 2304];             // per-wave 32x72 bf16 activation buffer
    const int tid = threadIdx.x, lane = tid & 63, wv = tid >> 6;
    const int n16 = lane & 15, kq = lane >> 4;

    // cooperative weight load: 11264 shorts = 1408 uint4
    {
        const uint4* src = (const uint4*)Bws;
        uint4* dst = (uint4*)W;
        for (int i = tid; i < 1408; i += 256) dst[i] = src[i];
    }
    __syncthreads();

    const int isbf = *flag;
    const long E0 = (long)blockIdx.x * 128 + wv * 32;
    short* Hw = Hs + wv * 2304;

    // ---- layer 1 A-fragments from edge_feats (K=8 padded to 32) ----
    short8 a1[2];
    #pragma unroll
    for (int mt = 0; mt < 2; mt++) {
        short8 a = {0,0,0,0,0,0,0,0};
        if (kq == 0) {
            long e = E0 + mt * 16 + n16;
            if (e > n_edges - 1) e = n_edges - 1;
            if (isbf) {
                a = *(const short8*)((const unsigned short*)ef + e * 8);
            } else {
                const float* pe = (const float*)ef + e * 8;
                float4 v0 = *(const float4*)pe, v1 = *(const float4*)(pe + 4);
                a[0]=fb2s(v0.x); a[1]=fb2s(v0.y); a[2]=fb2s(v0.z); a[3]=fb2s(v0.w);
                a[4]=fb2s(v1.x); a[5]=fb2s(v1.y); a[6]=fb2s(v1.z); a[7]=fb2s(v1.w);
            }
        }
        a1[mt] = a;
    }

    const f32x4 zero = {0.0f, 0.0f, 0.0f, 0.0f};

    // ---- layer 1 MFMA: [32x8] @ [8x64] ----
    {
        f32x4 c1[2][4];
        #pragma unroll
        for (int t = 0; t < 4; t++) {
            short8 b = *(const short8*)(W + t * 512 + lane * 8);
            #pragma unroll
            for (int mt = 0; mt < 2; mt++)
                c1[mt][t] = __builtin_amdgcn_mfma_f32_16x16x32_bf16(a1[mt], b, zero, 0, 0, 0);
        }
        #pragma unroll
        for (int mt = 0; mt < 2; mt++)
            #pragma unroll
            for (int t = 0; t < 4; t++)
                #pragma unroll
                for (int r = 0; r < 4; r++) {
                    float v = silu(c1[mt][t][r] * 0.35355339059327373f);
                    Hw[(mt * 16 + kq * 4 + r) * 72 + t * 16 + n16] = fb2s(v);
                }
    }

    // ---- layers 2,3: [32x64] @ [64x64] ----
    #pragma unroll
    for (int L = 0; L < 2; L++) {
        const int base = (L == 0) ? 4 : 12;
        short8 a[2][2];
        #pragma unroll
        for (int mt = 0; mt < 2; mt++)
            #pragma unroll
            for (int kt = 0; kt < 2; kt++)
                a[mt][kt] = *(const short8*)(Hw + (mt * 16 + n16) * 72 + kq * 8 + kt * 32);
        f32x4 c2[2][4];
        #pragma unroll
        for (int mt = 0; mt < 2; mt++)
            #pragma unroll
            for (int t = 0; t < 4; t++) c2[mt][t] = zero;
        #pragma unroll
        for (int kt = 0; kt < 2; kt++)
            #pragma unroll
            for (int t = 0; t < 4; t++) {
                short8 b = *(const short8*)(W + (base + t * 2 + kt) * 512 + lane * 8);
                #pragma unroll
                for (int mt = 0; mt < 2; mt++)
                    c2[mt][t] = __builtin_amdgcn_mfma_f32_16x16x32_bf16(a[mt][kt], b, c2[mt][t], 0, 0, 0);
            }
        #pragma unroll
        for (int mt = 0; mt < 2; mt++)
            #pragma unroll
            for (int t = 0; t < 4; t++)
                #pragma unroll
                for (int r = 0; r < 4; r++) {
                    float v = silu(c2[mt][t][r]);   // scale folded into weights
                    Hw[(mt * 16 + kq * 4 + r) * 72 + t * 16 + n16] = fb2s(v);
                }
    }

    // ---- layer 4: [32x64] @ [64x16] -> TP ----
    float* TP = (float*)Hw;                    // reuse per-wave region (32 x 17 f32)
    {
        short8 a[2][2];
        #pragma unroll
        for (int mt = 0; mt < 2; mt++)
            #pragma unroll
            for (int kt = 0; kt < 2; kt++)
                a[mt][kt] = *(const short8*)(Hw + (mt * 16 + n16) * 72 + kq * 8 + kt * 32);
        f32x4 c4[2] = {zero, zero};
        #pragma unroll
        for (int kt = 0; kt < 2; kt++) {
            short8 b = *(const short8*)(W + (20 + kt) * 512 + lane * 8);
            #pragma unroll
            for (int mt = 0; mt < 2; mt++)
                c4[mt] = __builtin_amdgcn_mfma_f32_16x16x32_bf16(a[mt][kt], b, c4[mt], 0, 0, 0);
        }
        #pragma unroll
        for (int mt = 0; mt < 2; mt++)
            #pragma unroll
            for (int r = 0; r < 4; r++)
                TP[(mt * 16 + kq * 4 + r) * 17 + n16] = c4[mt][r];
    }

    // ---- epilogue: 2 lanes per edge ----
    {
        const int el = lane >> 1, h = lane & 1;
        const long e = E0 + el;
        long ec = e;
        if (ec > n_edges - 1) ec = n_edges - 1;
        const int s = eidx[ec];
        const int r = eidx[(long)n_edges + ec];

        float tp0[4], tp1[4];
        #pragma unroll
        for (int i = 0; i < 4; i++) {
            tp0[i] = TP[el * 17 + h * 4 + i];
            tp1[i] = TP[el * 17 + 8 + h * 4 + i];
        }
        float q[4];
        load4(qc, (long)s * 8 + h * 4, isbf, q);
        float eav[4];
        load4(ea, ec * 4, isbf, eav);

        const float* nr = NA + (long)r * 32;
        float4 n0 = *(const float4*)(nr + h * 4);
        float t12[12];
        *(float4*)(t12 + 0) = *(const float4*)(nr + 8 + h * 12);
        *(float4*)(t12 + 4) = *(const float4*)(nr + 12 + h * 12);
        *(float4*)(t12 + 8) = *(const float4*)(nr + 16 + h * 12);

        float n0a[4] = {n0.x, n0.y, n0.z, n0.w};
        float p = 0.0f;
        #pragma unroll
        for (int i = 0; i < 4; i++) {
            float d = eav[1] * t12[i * 3] + eav[2] * t12[i * 3 + 1] + eav[3] * t12[i * 3 + 2];
            p += tp0[i] * q[i] * eav[0] * n0a[i] + tp1[i] * q[i] * d;
        }
        p += __shfl_xor(p, 1);
        if (h == 0 && e < n_edges) atomicAdd(&acc[r], p);
    }
}

// ---------- accumulator -> output ----------
__global__ void k_out(const float* __restrict__ acc, void* __restrict__ out,
                      const int* __restrict__ flag, int n) {
    int i = blockIdx.x * 256 + threadIdx.x;
    if (i >= n) return;
    if (*flag) ((__hip_bfloat16*)out)[i] = __float2bfloat16(acc[i]);
    else       ((float*)out)[i] = acc[i];
}

// ---------- launch ----------
extern "C" void kernel_launch(void* const* d_in, const int* in_sizes, int n_in,
                              void* d_out, int out_size, void* d_ws, size_t ws_size,
                              hipStream_t stream) {
    const void* node_feats      = d_in[0];
    const void* charges_induced = d_in[2];
    const void* edge_feats      = d_in[3];
    const void* edge_attrs      = d_in[4];
    const void* mlp_w1          = d_in[6];
    const void* mlp_w2          = d_in[7];
    const void* mlp_w3          = d_in[8];
    const void* mlp_w4          = d_in[9];
    const void* W0              = d_in[10];
    const void* W1              = d_in[11];
    const int*  edge_index      = (const int*)d_in[12];

    const int n_nodes = in_sizes[0] / 256;
    const int n_edges = in_sizes[3] / 8;

    int*   flag = (int*)d_ws;
    short* Bws  = (short*)((char*)d_ws + 256);                 // 11264 shorts = 22528 B
    float* NA   = (float*)((char*)d_ws + 256 + 22528);         // n_nodes*32 f32
    float* acc  = NA + (size_t)n_nodes * 32;                   // n_nodes f32

    k_detect<<<1, 64, 0, stream>>>((const unsigned int*)node_feats, flag);
    hipMemsetAsync(acc, 0, (size_t)n_nodes * sizeof(float), stream);
    k_prepack<<<44, 256, 0, stream>>>(mlp_w1, mlp_w2, mlp_w3, mlp_w4, flag, Bws);
    k_nodeA<<<(n_nodes + 3) / 4, 256, 0, stream>>>(node_feats, W0, W1, flag, NA, n_nodes);
    k_edges_mfma<<<(n_edges + 127) / 128, 256, 0, stream>>>(
        edge_feats, edge_attrs, charges_induced, edge_index, flag, Bws, NA, acc, n_edges);
    k_out<<<(n_nodes + 255) / 256, 256, 0, stream>>>(acc, d_out, flag, n_nodes);
}

// Round 4
// 340.853 us; speedup vs baseline: 2.9023x; 1.4735x over previous
//
#include <hip/hip_runtime.h>
#include <hip/hip_bf16.h>

typedef short short8 __attribute__((ext_vector_type(8)));
typedef float f32x4 __attribute__((ext_vector_type(4)));

// ---------- helpers ----------
static __device__ __forceinline__ float bf2f(unsigned int b) { return __uint_as_float(b << 16); }
static __device__ __forceinline__ short fb2s(float x) {       // f32 -> bf16 bits (RNE)
    unsigned u = __float_as_uint(x);
    return (short)((u + 0x7FFFu + ((u >> 16) & 1u)) >> 16);
}
static __device__ __forceinline__ float silu(float x) {
    // x * rcp(1+exp(-x)): v_rcp_f32 (~1 ulp) instead of the full v_div_* sequence
    return x * __builtin_amdgcn_rcpf(1.0f + __expf(-x));
}
static __device__ __forceinline__ float load1(const void* p, long off, int isbf) {
    return isbf ? bf2f(((const unsigned short*)p)[off]) : ((const float*)p)[off];
}
static __device__ __forceinline__ void load4(const void* p, long off, int isbf, float* o) {
    if (isbf) {
        uint2 v = *(const uint2*)((const unsigned short*)p + off);
        o[0]=bf2f(v.x&0xffffu); o[1]=bf2f(v.x>>16);
        o[2]=bf2f(v.y&0xffffu); o[3]=bf2f(v.y>>16);
    } else {
        float4 v = *(const float4*)((const float*)p + off);
        o[0]=v.x; o[1]=v.y; o[2]=v.z; o[3]=v.w;
    }
}

// ---------- dtype detector (bf16 vs f32) ----------
__global__ void k_detect(const unsigned int* __restrict__ w, int* __restrict__ flag) {
    int lane = threadIdx.x & 63;
    unsigned int e = (w[lane] >> 7) & 0xFFu;
    unsigned long long m = __ballot(e >= 118u && e <= 132u);
    if (lane == 0) *flag = (__popcll(m) >= 32) ? 1 : 0;
}

// ---------- prepack MLP weights into MFMA B-fragment layout (bf16) ----------
__global__ void k_prepack(const void* __restrict__ w1, const void* __restrict__ w2,
                          const void* __restrict__ w3, const void* __restrict__ w4,
                          const int* __restrict__ flag, short* __restrict__ Bws) {
    int idx = blockIdx.x * 256 + threadIdx.x;
    if (idx >= 11264) return;
    const int isbf = *flag;
    int j = idx & 7, lane = (idx >> 3) & 63, tile = idx >> 9;
    int n16 = lane & 15, kq = lane >> 4;
    float v;
    if (tile < 4) {
        int k = kq * 8 + j, n = tile * 16 + n16;
        v = (k < 8) ? load1(w1, k * 64 + n, isbf) : 0.0f;
    } else if (tile < 12) {
        int t = (tile - 4) >> 1, kt = (tile - 4) & 1;
        int k = kt * 32 + kq * 8 + j, n = t * 16 + n16;
        v = load1(w2, k * 64 + n, isbf) * 0.125f;
    } else if (tile < 20) {
        int t = (tile - 12) >> 1, kt = (tile - 12) & 1;
        int k = kt * 32 + kq * 8 + j, n = t * 16 + n16;
        v = load1(w3, k * 64 + n, isbf) * 0.125f;
    } else {
        int kt = tile - 20;
        int k = kt * 32 + kq * 8 + j, n = n16;
        v = load1(w4, k * 16 + n, isbf) * 0.125f;
    }
    Bws[idx] = fb2s(v);
}

// ---------- per-node projections: 32 nodes/block, LDS-tiled, wave-uniform ----------
#define NB 32
__global__ __launch_bounds__(256) void k_nodeA(
    const void* __restrict__ nf, const void* __restrict__ W0, const void* __restrict__ W1,
    const int* __restrict__ flag, float* __restrict__ NA, int n_nodes) {
    __shared__ float Nd0[NB * 68];          // node0: [node][64 + pad4]
    __shared__ float Nd1[3 * NB * 68];      // node1: [kk][node][64 + pad4]
    __shared__ float W0L[8 * 68];
    __shared__ float W1L[8 * 68];
    const int tid = threadIdx.x;
    const int isbf = *flag;
    const long n0 = (long)blockIdx.x * NB;

    for (int i = tid; i < 512; i += 256) {
        W0L[(i >> 6) * 68 + (i & 63)] = load1(W0, i, isbf);
        W1L[(i >> 6) * 68 + (i & 63)] = load1(W1, i, isbf);
    }
    if (isbf) {
        for (int i = tid; i < NB * 32; i += 256) {     // uint4 = 8 bf16
            int node = i >> 5, c8 = (i & 31) * 8;
            long ng = n0 + node; if (ng > n_nodes - 1) ng = n_nodes - 1;
            uint4 v = *(const uint4*)((const unsigned short*)nf + ng * 256 + c8);
            float f[8];
            f[0]=bf2f(v.x&0xffffu); f[1]=bf2f(v.x>>16);
            f[2]=bf2f(v.y&0xffffu); f[3]=bf2f(v.y>>16);
            f[4]=bf2f(v.z&0xffffu); f[5]=bf2f(v.z>>16);
            f[6]=bf2f(v.w&0xffffu); f[7]=bf2f(v.w>>16);
            #pragma unroll
            for (int t = 0; t < 8; t++) {
                int col = c8 + t;
                if (col < 64) Nd0[node * 68 + col] = f[t];
                else {
                    int cc = col - 64, vv = cc / 3, kk = cc - vv * 3;
                    Nd1[(kk * NB + node) * 68 + vv] = f[t];
                }
            }
        }
    } else {
        for (int i = tid; i < NB * 64; i += 256) {     // float4
            int node = i >> 6, c4 = (i & 63) * 4;
            long ng = n0 + node; if (ng > n_nodes - 1) ng = n_nodes - 1;
            float4 v = *(const float4*)((const float*)nf + ng * 256 + c4);
            float f[4] = {v.x, v.y, v.z, v.w};
            #pragma unroll
            for (int t = 0; t < 4; t++) {
                int col = c4 + t;
                if (col < 64) Nd0[node * 68 + col] = f[t];
                else {
                    int cc = col - 64, vv = cc / 3, kk = cc - vv * 3;
                    Nd1[(kk * NB + node) * 68 + vv] = f[t];
                }
            }
        }
    }
    __syncthreads();

    const int wv = tid >> 6, lane = tid & 63;
    const int u = lane & 7, ln = lane >> 3;
    float sum[4] = {0.0f, 0.0f, 0.0f, 0.0f};

    if (wv == 0) {                                    // A0 outputs: c = u
        const float* w = &W0L[u * 68];
        for (int v0 = 0; v0 < 64; v0 += 4) {
            float4 w4 = *(const float4*)(w + v0);
            #pragma unroll
            for (int j = 0; j < 4; j++) {
                float4 nd = *(const float4*)&Nd0[(ln + 8 * j) * 68 + v0];
                sum[j] += w4.x * nd.x + w4.y * nd.y + w4.z * nd.z + w4.w * nd.w;
            }
        }
        #pragma unroll
        for (int j = 0; j < 4; j++) {
            long node = n0 + ln + 8 * j;
            if (node < n_nodes) NA[node * 32 + u] = sum[j] * 0.03125f;
        }
    } else {                                          // A1 outputs: c = 8 + u*3 + kk
        const int kk = wv - 1;
        const float* w = &W1L[u * 68];
        const float* nd1 = &Nd1[kk * NB * 68];
        for (int v0 = 0; v0 < 64; v0 += 4) {
            float4 w4 = *(const float4*)(w + v0);
            #pragma unroll
            for (int j = 0; j < 4; j++) {
                float4 nd = *(const float4*)&nd1[(ln + 8 * j) * 68 + v0];
                sum[j] += w4.x * nd.x + w4.y * nd.y + w4.z * nd.z + w4.w * nd.w;
            }
        }
        #pragma unroll
        for (int j = 0; j < 4; j++) {
            long node = n0 + ln + 8 * j;
            if (node < n_nodes) NA[node * 32 + 8 + u * 3 + kk] = sum[j] * 0.018042195912175804f;
        }
    }
}

// ---------- MFMA edge kernel: 256 thr = 4 waves, 32 edges/wave ----------
__global__ __launch_bounds__(256) void k_edges_mfma(
    const void* __restrict__ ef, const void* __restrict__ ea, const void* __restrict__ qc,
    const int* __restrict__ eidx, const int* __restrict__ flag,
    const short* __restrict__ Bws, const float* __restrict__ NA,
    float* __restrict__ acc, int n_edges) {
    __shared__ short W[11264];
    __shared__ short Hs[4 * 2304];
    const int tid = threadIdx.x, lane = tid & 63, wv = tid >> 6;
    const int n16 = lane & 15, kq = lane >> 4;

    {
        const uint4* src = (const uint4*)Bws;
        uint4* dst = (uint4*)W;
        for (int i = tid; i < 1408; i += 256) dst[i] = src[i];
    }
    __syncthreads();

    const int isbf = *flag;
    const long E0 = (long)blockIdx.x * 128 + wv * 32;
    short* Hw = Hs + wv * 2304;

    short8 a1[2];
    #pragma unroll
    for (int mt = 0; mt < 2; mt++) {
        short8 a = {0,0,0,0,0,0,0,0};
        if (kq == 0) {
            long e = E0 + mt * 16 + n16;
            if (e > n_edges - 1) e = n_edges - 1;
            if (isbf) {
                a = *(const short8*)((const unsigned short*)ef + e * 8);
            } else {
                const float* pe = (const float*)ef + e * 8;
                float4 v0 = *(const float4*)pe, v1 = *(const float4*)(pe + 4);
                a[0]=fb2s(v0.x); a[1]=fb2s(v0.y); a[2]=fb2s(v0.z); a[3]=fb2s(v0.w);
                a[4]=fb2s(v1.x); a[5]=fb2s(v1.y); a[6]=fb2s(v1.z); a[7]=fb2s(v1.w);
            }
        }
        a1[mt] = a;
    }

    const f32x4 zero = {0.0f, 0.0f, 0.0f, 0.0f};

    {   // layer 1
        f32x4 c1[2][4];
        #pragma unroll
        for (int t = 0; t < 4; t++) {
            short8 b = *(const short8*)(W + t * 512 + lane * 8);
            #pragma unroll
            for (int mt = 0; mt < 2; mt++)
                c1[mt][t] = __builtin_amdgcn_mfma_f32_16x16x32_bf16(a1[mt], b, zero, 0, 0, 0);
        }
        #pragma unroll
        for (int mt = 0; mt < 2; mt++)
            #pragma unroll
            for (int t = 0; t < 4; t++)
                #pragma unroll
                for (int r = 0; r < 4; r++) {
                    float v = silu(c1[mt][t][r] * 0.35355339059327373f);
                    Hw[(mt * 16 + kq * 4 + r) * 72 + t * 16 + n16] = fb2s(v);
                }
    }

    #pragma unroll
    for (int L = 0; L < 2; L++) {   // layers 2,3
        const int base = (L == 0) ? 4 : 12;
        short8 a[2][2];
        #pragma unroll
        for (int mt = 0; mt < 2; mt++)
            #pragma unroll
            for (int kt = 0; kt < 2; kt++)
                a[mt][kt] = *(const short8*)(Hw + (mt * 16 + n16) * 72 + kq * 8 + kt * 32);
        f32x4 c2[2][4];
        #pragma unroll
        for (int mt = 0; mt < 2; mt++)
            #pragma unroll
            for (int t = 0; t < 4; t++) c2[mt][t] = zero;
        #pragma unroll
        for (int kt = 0; kt < 2; kt++)
            #pragma unroll
            for (int t = 0; t < 4; t++) {
                short8 b = *(const short8*)(W + (base + t * 2 + kt) * 512 + lane * 8);
                #pragma unroll
                for (int mt = 0; mt < 2; mt++)
                    c2[mt][t] = __builtin_amdgcn_mfma_f32_16x16x32_bf16(a[mt][kt], b, c2[mt][t], 0, 0, 0);
            }
        #pragma unroll
        for (int mt = 0; mt < 2; mt++)
            #pragma unroll
            for (int t = 0; t < 4; t++)
                #pragma unroll
                for (int r = 0; r < 4; r++) {
                    float v = silu(c2[mt][t][r]);
                    Hw[(mt * 16 + kq * 4 + r) * 72 + t * 16 + n16] = fb2s(v);
                }
    }

    float* TP = (float*)Hw;         // layer 4 -> 32 x 17 f32
    {
        short8 a[2][2];
        #pragma unroll
        for (int mt = 0; mt < 2; mt++)
            #pragma unroll
            for (int kt = 0; kt < 2; kt++)
                a[mt][kt] = *(const short8*)(Hw + (mt * 16 + n16) * 72 + kq * 8 + kt * 32);
        f32x4 c4[2] = {zero, zero};
        #pragma unroll
        for (int kt = 0; kt < 2; kt++) {
            short8 b = *(const short8*)(W + (20 + kt) * 512 + lane * 8);
            #pragma unroll
            for (int mt = 0; mt < 2; mt++)
                c4[mt] = __builtin_amdgcn_mfma_f32_16x16x32_bf16(a[mt][kt], b, c4[mt], 0, 0, 0);
        }
        #pragma unroll
        for (int mt = 0; mt < 2; mt++)
            #pragma unroll
            for (int r = 0; r < 4; r++)
                TP[(mt * 16 + kq * 4 + r) * 17 + n16] = c4[mt][r];
    }

    {   // epilogue: 2 lanes per edge
        const int el = lane >> 1, h = lane & 1;
        const long e = E0 + el;
        long ec = e;
        if (ec > n_edges - 1) ec = n_edges - 1;
        const int s = eidx[ec];
        const int r = eidx[(long)n_edges + ec];

        float tp0[4], tp1[4];
        #pragma unroll
        for (int i = 0; i < 4; i++) {
            tp0[i] = TP[el * 17 + h * 4 + i];
            tp1[i] = TP[el * 17 + 8 + h * 4 + i];
        }
        float q[4];
        load4(qc, (long)s * 8 + h * 4, isbf, q);
        float eav[4];
        load4(ea, ec * 4, isbf, eav);

        const float* nr = NA + (long)r * 32;
        float4 n0 = *(const float4*)(nr + h * 4);
        float t12[12];
        *(float4*)(t12 + 0) = *(const float4*)(nr + 8 + h * 12);
        *(float4*)(t12 + 4) = *(const float4*)(nr + 12 + h * 12);
        *(float4*)(t12 + 8) = *(const float4*)(nr + 16 + h * 12);

        float n0a[4] = {n0.x, n0.y, n0.z, n0.w};
        float p = 0.0f;
        #pragma unroll
        for (int i = 0; i < 4; i++) {
            float d = eav[1] * t12[i * 3] + eav[2] * t12[i * 3 + 1] + eav[3] * t12[i * 3 + 2];
            p += tp0[i] * q[i] * eav[0] * n0a[i] + tp1[i] * q[i] * d;
        }
        p += __shfl_xor(p, 1);
        if (h == 0 && e < n_edges) atomicAdd(&acc[r], p);
    }
}

// ---------- accumulator -> output ----------
__global__ void k_out(const float* __restrict__ acc, void* __restrict__ out,
                      const int* __restrict__ flag, int n) {
    int i = blockIdx.x * 256 + threadIdx.x;
    if (i >= n) return;
    if (*flag) ((__hip_bfloat16*)out)[i] = __float2bfloat16(acc[i]);
    else       ((float*)out)[i] = acc[i];
}

// ---------- launch ----------
extern "C" void kernel_launch(void* const* d_in, const int* in_sizes, int n_in,
                              void* d_out, int out_size, void* d_ws, size_t ws_size,
                              hipStream_t stream) {
    const void* node_feats      = d_in[0];
    const void* charges_induced = d_in[2];
    const void* edge_feats      = d_in[3];
    const void* edge_attrs      = d_in[4];
    const void* mlp_w1          = d_in[6];
    const void* mlp_w2          = d_in[7];
    const void* mlp_w3          = d_in[8];
    const void* mlp_w4          = d_in[9];
    const void* W0              = d_in[10];
    const void* W1              = d_in[11];
    const int*  edge_index      = (const int*)d_in[12];

    const int n_nodes = in_sizes[0] / 256;
    const int n_edges = in_sizes[3] / 8;

    int*   flag = (int*)d_ws;
    short* Bws  = (short*)((char*)d_ws + 256);
    float* NA   = (float*)((char*)d_ws + 256 + 22528);
    float* acc  = NA + (size_t)n_nodes * 32;

    k_detect<<<1, 64, 0, stream>>>((const unsigned int*)node_feats, flag);
    hipMemsetAsync(acc, 0, (size_t)n_nodes * sizeof(float), stream);
    k_prepack<<<44, 256, 0, stream>>>(mlp_w1, mlp_w2, mlp_w3, mlp_w4, flag, Bws);
    k_nodeA<<<(n_nodes + NB - 1) / NB, 256, 0, stream>>>(node_feats, W0, W1, flag, NA, n_nodes);
    k_edges_mfma<<<(n_edges + 127) / 128, 256, 0, stream>>>(
        edge_feats, edge_attrs, charges_induced, edge_index, flag, Bws, NA, acc, n_edges);
    k_out<<<(n_nodes + 255) / 256, 256, 0, stream>>>(acc, d_out, flag, n_nodes);
}

// Round 5
// 337.303 us; speedup vs baseline: 2.9328x; 1.0105x over previous
//
#include <hip/hip_runtime.h>
#include <hip/hip_bf16.h>

typedef short short8 __attribute__((ext_vector_type(8)));
typedef float f32x4 __attribute__((ext_vector_type(4)));

// ---------- helpers ----------
static __device__ __forceinline__ float bf2f(unsigned int b) { return __uint_as_float(b << 16); }
static __device__ __forceinline__ short fb2s(float x) {       // f32 -> bf16 (RNE, for prepack)
    unsigned u = __float_as_uint(x);
    return (short)((u + 0x7FFFu + ((u >> 16) & 1u)) >> 16);
}
static __device__ __forceinline__ short fb2s_fast(float x) {  // f32 -> bf16 (round-half-up, 2 ops)
    return (short)((__float_as_uint(x) + 0x8000u) >> 16);
}
static __device__ __forceinline__ float silu(float x) {
    return x * __builtin_amdgcn_rcpf(1.0f + __expf(-x));
}
static __device__ __forceinline__ float load1(const void* p, long off, int isbf) {
    return isbf ? bf2f(((const unsigned short*)p)[off]) : ((const float*)p)[off];
}
static __device__ __forceinline__ void load4(const void* p, long off, int isbf, float* o) {
    if (isbf) {
        uint2 v = *(const uint2*)((const unsigned short*)p + off);
        o[0]=bf2f(v.x&0xffffu); o[1]=bf2f(v.x>>16);
        o[2]=bf2f(v.y&0xffffu); o[3]=bf2f(v.y>>16);
    } else {
        float4 v = *(const float4*)((const float*)p + off);
        o[0]=v.x; o[1]=v.y; o[2]=v.z; o[3]=v.w;
    }
}
// per-wave dtype detection (deterministic, wave-uniform; no barrier needed)
static __device__ __forceinline__ int detect_bf16(const void* nf) {
    const unsigned int* w = (const unsigned int*)nf;
    int lane = threadIdx.x & 63;
    unsigned int e = (w[lane] >> 7) & 0xFFu;
    unsigned long long m = __ballot(e >= 118u && e <= 132u);
    return __popcll(m) >= 32 ? 1 : 0;
}

// ---------- fused kernel: prepack (blocks 0..43) + acc zero + per-node projections ----------
#define NB 32
__global__ __launch_bounds__(256) void k_node(
    const void* __restrict__ nf, const void* __restrict__ W0, const void* __restrict__ W1,
    const void* __restrict__ w1, const void* __restrict__ w2,
    const void* __restrict__ w3, const void* __restrict__ w4,
    short* __restrict__ Bws, float* __restrict__ NA, float* __restrict__ acc, int n_nodes) {
    __shared__ float Nd0[NB * 68];
    __shared__ float Nd1[3 * NB * 68];
    __shared__ float W0L[8 * 68];
    __shared__ float W1L[8 * 68];
    const int tid = threadIdx.x;
    const int isbf = detect_bf16(nf);
    const long n0 = (long)blockIdx.x * NB;

    // --- prepack MLP weights into MFMA B-fragment layout (first 44 blocks) ---
    if (blockIdx.x < 44) {
        int idx = blockIdx.x * 256 + tid;
        int j = idx & 7, lane = (idx >> 3) & 63, tile = idx >> 9;
        int n16 = lane & 15, kq = lane >> 4;
        float v;
        if (tile < 4) {
            int k = kq * 8 + j, n = tile * 16 + n16;
            v = (k < 8) ? load1(w1, k * 64 + n, isbf) : 0.0f;
        } else if (tile < 12) {
            int t = (tile - 4) >> 1, kt = (tile - 4) & 1;
            int k = kt * 32 + kq * 8 + j, n = t * 16 + n16;
            v = load1(w2, k * 64 + n, isbf) * 0.125f;
        } else if (tile < 20) {
            int t = (tile - 12) >> 1, kt = (tile - 12) & 1;
            int k = kt * 32 + kq * 8 + j, n = t * 16 + n16;
            v = load1(w3, k * 64 + n, isbf) * 0.125f;
        } else {
            int kt = tile - 20;
            int k = kt * 32 + kq * 8 + j, n = n16;
            v = load1(w4, k * 16 + n, isbf) * 0.125f;
        }
        Bws[idx] = fb2s(v);
    }
    // --- zero the edge accumulator ---
    if (tid < NB) {
        long n = n0 + tid;
        if (n < n_nodes) acc[n] = 0.0f;
    }
    if (n0 >= n_nodes) return;   // pure-prepack block (grid = max(nblk,44))

    // --- stage node_feats ---
    for (int i = tid; i < 512; i += 256) {
        W0L[(i >> 6) * 68 + (i & 63)] = load1(W0, i, isbf);
        W1L[(i >> 6) * 68 + (i & 63)] = load1(W1, i, isbf);
    }
    if (isbf) {
        for (int i = tid; i < NB * 32; i += 256) {
            int node = i >> 5, c8 = (i & 31) * 8;
            long ng = n0 + node; if (ng > n_nodes - 1) ng = n_nodes - 1;
            uint4 v = *(const uint4*)((const unsigned short*)nf + ng * 256 + c8);
            float f[8];
            f[0]=bf2f(v.x&0xffffu); f[1]=bf2f(v.x>>16);
            f[2]=bf2f(v.y&0xffffu); f[3]=bf2f(v.y>>16);
            f[4]=bf2f(v.z&0xffffu); f[5]=bf2f(v.z>>16);
            f[6]=bf2f(v.w&0xffffu); f[7]=bf2f(v.w>>16);
            #pragma unroll
            for (int t = 0; t < 8; t++) {
                int col = c8 + t;
                if (col < 64) Nd0[node * 68 + col] = f[t];
                else {
                    int cc = col - 64, vv = cc / 3, kk = cc - vv * 3;
                    Nd1[(kk * NB + node) * 68 + vv] = f[t];
                }
            }
        }
    } else {
        for (int i = tid; i < NB * 64; i += 256) {
            int node = i >> 6, c4 = (i & 63) * 4;
            long ng = n0 + node; if (ng > n_nodes - 1) ng = n_nodes - 1;
            float4 v = *(const float4*)((const float*)nf + ng * 256 + c4);
            float f[4] = {v.x, v.y, v.z, v.w};
            #pragma unroll
            for (int t = 0; t < 4; t++) {
                int col = c4 + t;
                if (col < 64) Nd0[node * 68 + col] = f[t];
                else {
                    int cc = col - 64, vv = cc / 3, kk = cc - vv * 3;
                    Nd1[(kk * NB + node) * 68 + vv] = f[t];
                }
            }
        }
    }
    __syncthreads();

    const int wv = tid >> 6, lane = tid & 63;
    const int u = lane & 7, ln = lane >> 3;
    float sum[4] = {0.0f, 0.0f, 0.0f, 0.0f};

    if (wv == 0) {
        const float* w = &W0L[u * 68];
        for (int v0 = 0; v0 < 64; v0 += 4) {
            float4 w4 = *(const float4*)(w + v0);
            #pragma unroll
            for (int j = 0; j < 4; j++) {
                float4 nd = *(const float4*)&Nd0[(ln + 8 * j) * 68 + v0];
                sum[j] += w4.x * nd.x + w4.y * nd.y + w4.z * nd.z + w4.w * nd.w;
            }
        }
        #pragma unroll
        for (int j = 0; j < 4; j++) {
            long node = n0 + ln + 8 * j;
            if (node < n_nodes) NA[node * 32 + u] = sum[j] * 0.03125f;
        }
    } else {
        const int kk = wv - 1;
        const float* w = &W1L[u * 68];
        const float* nd1 = &Nd1[kk * NB * 68];
        for (int v0 = 0; v0 < 64; v0 += 4) {
            float4 w4 = *(const float4*)(w + v0);
            #pragma unroll
            for (int j = 0; j < 4; j++) {
                float4 nd = *(const float4*)&nd1[(ln + 8 * j) * 68 + v0];
                sum[j] += w4.x * nd.x + w4.y * nd.y + w4.z * nd.z + w4.w * nd.w;
            }
        }
        #pragma unroll
        for (int j = 0; j < 4; j++) {
            long node = n0 + ln + 8 * j;
            if (node < n_nodes) NA[node * 32 + 8 + u * 3 + kk] = sum[j] * 0.018042195912175804f;
        }
    }
}

// ---------- MFMA edge kernel ----------
// H layout: physical short idx = row*72 + ((col>>3) ^ ((row>>3)&1))*8 + (col&7)
// -> breaks the kq0/kq2 4-way write conflict, preserves 16B-aligned b128 reads.
__global__ __launch_bounds__(256) void k_edges_mfma(
    const void* __restrict__ ef, const void* __restrict__ ea, const void* __restrict__ qc,
    const int* __restrict__ eidx, const void* __restrict__ nf,
    const short* __restrict__ Bws, const float* __restrict__ NA,
    float* __restrict__ acc, int n_edges) {
    __shared__ short W[11264];
    __shared__ short Hs[4 * 2304];
    const int tid = threadIdx.x, lane = tid & 63, wv = tid >> 6;
    const int n16 = lane & 15, kq = lane >> 4;
    const int isbf = detect_bf16(nf);

    {
        const uint4* src = (const uint4*)Bws;
        uint4* dst = (uint4*)W;
        for (int i = tid; i < 1408; i += 256) dst[i] = src[i];
    }
    __syncthreads();

    const long E0 = (long)blockIdx.x * 128 + wv * 32;
    short* Hw = Hs + wv * 2304;

    // per-lane swizzled column-group offsets (shorts) for writes: col = t*16+n16
    int woff[4];
    #pragma unroll
    for (int t = 0; t < 4; t++)
        woff[t] = (((t * 2 + (n16 >> 3)) ^ (kq >> 1)) << 3) + (n16 & 7);
    const int rbit = (n16 >> 3) & 1;   // read-side swizzle bit

    short8 a1[2];
    #pragma unroll
    for (int mt = 0; mt < 2; mt++) {
        short8 a = {0,0,0,0,0,0,0,0};
        if (kq == 0) {
            long e = E0 + mt * 16 + n16;
            if (e > n_edges - 1) e = n_edges - 1;
            if (isbf) {
                a = *(const short8*)((const unsigned short*)ef + e * 8);
            } else {
                const float* pe = (const float*)ef + e * 8;
                float4 v0 = *(const float4*)pe, v1 = *(const float4*)(pe + 4);
                a[0]=fb2s(v0.x); a[1]=fb2s(v0.y); a[2]=fb2s(v0.z); a[3]=fb2s(v0.w);
                a[4]=fb2s(v1.x); a[5]=fb2s(v1.y); a[6]=fb2s(v1.z); a[7]=fb2s(v1.w);
            }
        }
        a1[mt] = a;
    }

    const f32x4 zero = {0.0f, 0.0f, 0.0f, 0.0f};

    {   // layer 1: [32x8pad32] @ [8x64]
        f32x4 c1[2][4];
        #pragma unroll
        for (int t = 0; t < 4; t++) {
            short8 b = *(const short8*)(W + t * 512 + lane * 8);
            #pragma unroll
            for (int mt = 0; mt < 2; mt++)
                c1[mt][t] = __builtin_amdgcn_mfma_f32_16x16x32_bf16(a1[mt], b, zero, 0, 0, 0);
        }
        #pragma unroll
        for (int mt = 0; mt < 2; mt++)
            #pragma unroll
            for (int t = 0; t < 4; t++)
                #pragma unroll
                for (int r = 0; r < 4; r++) {
                    float v = silu(c1[mt][t][r] * 0.35355339059327373f);
                    Hw[(mt * 16 + kq * 4 + r) * 72 + woff[t]] = fb2s_fast(v);
                }
    }

    #pragma unroll
    for (int L = 0; L < 2; L++) {   // layers 2,3: [32x64] @ [64x64]
        const int base = (L == 0) ? 4 : 12;
        short8 a[2][2];
        #pragma unroll
        for (int mt = 0; mt < 2; mt++)
            #pragma unroll
            for (int kt = 0; kt < 2; kt++)
                a[mt][kt] = *(const short8*)(Hw + (mt * 16 + n16) * 72 + (((kt * 4 + kq) ^ rbit) << 3));
        f32x4 c2[2][4];
        #pragma unroll
        for (int mt = 0; mt < 2; mt++)
            #pragma unroll
            for (int t = 0; t < 4; t++) c2[mt][t] = zero;
        #pragma unroll
        for (int kt = 0; kt < 2; kt++)
            #pragma unroll
            for (int t = 0; t < 4; t++) {
                short8 b = *(const short8*)(W + (base + t * 2 + kt) * 512 + lane * 8);
                #pragma unroll
                for (int mt = 0; mt < 2; mt++)
                    c2[mt][t] = __builtin_amdgcn_mfma_f32_16x16x32_bf16(a[mt][kt], b, c2[mt][t], 0, 0, 0);
            }
        #pragma unroll
        for (int mt = 0; mt < 2; mt++)
            #pragma unroll
            for (int t = 0; t < 4; t++)
                #pragma unroll
                for (int r = 0; r < 4; r++) {
                    float v = silu(c2[mt][t][r]);
                    Hw[(mt * 16 + kq * 4 + r) * 72 + woff[t]] = fb2s_fast(v);
                }
    }

    float* TP = (float*)Hw;   // layer 4 output: 32 rows x stride 20 f32 (16B-aligned rows)
    {
        short8 a[2][2];
        #pragma unroll
        for (int mt = 0; mt < 2; mt++)
            #pragma unroll
            for (int kt = 0; kt < 2; kt++)
                a[mt][kt] = *(const short8*)(Hw + (mt * 16 + n16) * 72 + (((kt * 4 + kq) ^ rbit) << 3));
        f32x4 c4[2] = {zero, zero};
        #pragma unroll
        for (int kt = 0; kt < 2; kt++) {
            short8 b = *(const short8*)(W + (20 + kt) * 512 + lane * 8);
            #pragma unroll
            for (int mt = 0; mt < 2; mt++)
                c4[mt] = __builtin_amdgcn_mfma_f32_16x16x32_bf16(a[mt][kt], b, c4[mt], 0, 0, 0);
        }
        #pragma unroll
        for (int mt = 0; mt < 2; mt++)
            #pragma unroll
            for (int r = 0; r < 4; r++)
                TP[(mt * 16 + kq * 4 + r) * 20 + n16] = c4[mt][r];
    }

    {   // epilogue: 2 lanes per edge
        const int el = lane >> 1, h = lane & 1;
        const long e = E0 + el;
        long ec = e;
        if (ec > n_edges - 1) ec = n_edges - 1;
        const int s = eidx[ec];
        const int r = eidx[(long)n_edges + ec];

        float4 t0 = *(const float4*)(TP + el * 20 + h * 4);
        float4 t1 = *(const float4*)(TP + el * 20 + 8 + h * 4);
        float tp0[4] = {t0.x, t0.y, t0.z, t0.w};
        float tp1[4] = {t1.x, t1.y, t1.z, t1.w};

        float q[4];
        load4(qc, (long)s * 8 + h * 4, isbf, q);
        float eav[4];
        load4(ea, ec * 4, isbf, eav);

        const float* nr = NA + (long)r * 32;
        float4 n0 = *(const float4*)(nr + h * 4);
        float t12[12];
        *(float4*)(t12 + 0) = *(const float4*)(nr + 8 + h * 12);
        *(float4*)(t12 + 4) = *(const float4*)(nr + 12 + h * 12);
        *(float4*)(t12 + 8) = *(const float4*)(nr + 16 + h * 12);

        float n0a[4] = {n0.x, n0.y, n0.z, n0.w};
        float p = 0.0f;
        #pragma unroll
        for (int i = 0; i < 4; i++) {
            float d = eav[1] * t12[i * 3] + eav[2] * t12[i * 3 + 1] + eav[3] * t12[i * 3 + 2];
            p += tp0[i] * q[i] * eav[0] * n0a[i] + tp1[i] * q[i] * d;
        }
        p += __shfl_xor(p, 1);
        if (h == 0 && e < n_edges) atomicAdd(&acc[r], p);
    }
}

// ---------- accumulator -> output ----------
__global__ void k_out(const float* __restrict__ acc, void* __restrict__ out,
                      const void* __restrict__ nf, int n) {
    const int isbf = detect_bf16(nf);
    int i = blockIdx.x * 256 + threadIdx.x;
    if (i >= n) return;
    if (isbf) ((__hip_bfloat16*)out)[i] = __float2bfloat16(acc[i]);
    else      ((float*)out)[i] = acc[i];
}

// ---------- launch ----------
extern "C" void kernel_launch(void* const* d_in, const int* in_sizes, int n_in,
                              void* d_out, int out_size, void* d_ws, size_t ws_size,
                              hipStream_t stream) {
    const void* node_feats      = d_in[0];
    const void* charges_induced = d_in[2];
    const void* edge_feats      = d_in[3];
    const void* edge_attrs      = d_in[4];
    const void* mlp_w1          = d_in[6];
    const void* mlp_w2          = d_in[7];
    const void* mlp_w3          = d_in[8];
    const void* mlp_w4          = d_in[9];
    const void* W0              = d_in[10];
    const void* W1              = d_in[11];
    const int*  edge_index      = (const int*)d_in[12];

    const int n_nodes = in_sizes[0] / 256;
    const int n_edges = in_sizes[3] / 8;

    short* Bws = (short*)d_ws;                                 // 11264 shorts
    float* NA  = (float*)((char*)d_ws + 22528);                // n_nodes*32 f32
    float* acc = NA + (size_t)n_nodes * 32;                    // n_nodes f32

    int nblk = (n_nodes + NB - 1) / NB;
    if (nblk < 44) nblk = 44;
    k_node<<<nblk, 256, 0, stream>>>(node_feats, W0, W1,
        mlp_w1, mlp_w2, mlp_w3, mlp_w4, Bws, NA, acc, n_nodes);
    k_edges_mfma<<<(n_edges + 127) / 128, 256, 0, stream>>>(
        edge_feats, edge_attrs, charges_induced, edge_index, node_feats, Bws, NA, acc, n_edges);
    k_out<<<(n_nodes + 255) / 256, 256, 0, stream>>>(acc, d_out, node_feats, n_nodes);
}